// Round 4
// baseline (887.958 us; speedup 1.0000x reference)
//
#include <hip/hip_runtime.h>
#include <math.h>
#include <stdint.h>

#define N_NODES 50000
#define N_EDGES 500000
#define D 128
#define BE 128         // edges per block (M tile)
#define NKT 6          // 384 / 64 K-tiles
#define WROW 72        // LDS row stride in bf16 (64 real + 8 pad, pad never read)
#define WSLAB (256 * WROW)
#define LOG2E 1.4426950408889634f
#define LN2   0.6931471805599453f

typedef __attribute__((ext_vector_type(8))) short bf16x8;
typedef __attribute__((ext_vector_type(4))) float floatx4;

__device__ __forceinline__ float fast_sigmoid(float v) {
    return __builtin_amdgcn_rcpf(1.0f + __builtin_amdgcn_exp2f(-v * LOG2E));
}
__device__ __forceinline__ float fast_softplus(float v) {
    float t = __builtin_amdgcn_exp2f(-fabsf(v) * LOG2E);
    return fmaxf(v, 0.0f) + __builtin_amdgcn_logf(1.0f + t) * LN2;
}
// round-half-up bf16 pair pack: (add, add, v_perm)
__device__ __forceinline__ uint32_t pack_bf16(float a, float b) {
    union { float f; uint32_t u; } ca, cb; ca.f = a; cb.f = b;
    return __builtin_amdgcn_perm(cb.u + 0x8000u, ca.u + 0x8000u, 0x07060302);
}

// Wt layout: [kt=0..5][i=0..7][n=0..255] x uint4, where uint4 = bf16[8] of
// W[n][kt*64 + i*8 .. +8]  (n<128: Wf col n; else Ws col n-128).
// Both producer (here) and consumer (edge kernel) are lane-coalesced.
__global__ __launch_bounds__(256) void wt_prepass(
    const float* __restrict__ Wf, const float* __restrict__ Ws,
    uint4* __restrict__ Wt)
{
    const int kt = blockIdx.x >> 3;
    const int i  = blockIdx.x & 7;
    const int n  = threadIdx.x;
    const float* src = (n < 128) ? (Wf + n) : (Ws + (n - 128));
    const int k0 = kt * 64 + i * 8;
    uint32_t u[4];
#pragma unroll
    for (int j = 0; j < 4; j++) {
        float a = src[(size_t)(k0 + 2 * j) * D];
        float b = src[(size_t)(k0 + 2 * j + 1) * D];
        u[j] = pack_bf16(a, b);
    }
    uint4 v; v.x = u[0]; v.y = u[1]; v.z = u[2]; v.w = u[3];
    Wt[(size_t)(kt * 8 + i) * 256 + n] = v;
}

// Per block: 128 edges x 256 outputs (128 f + 128 s), K=384, bf16 MFMA
// 16x16x32. Register-pipelined: W[kt+1]/Z[kt+1] global->reg loads issue at
// the top of the MFMA section of kt and drain at its trailing barrier.
// Wave w owns f-cols [w*32,w*32+32) + matching s-cols: gate pairs
// acc[mt][nt] (f) with acc[mt][nt+2] (s) on the same lane/register.
__global__ __launch_bounds__(256, 2) void edge_msg_mfma(
    const float* __restrict__ x, const float* __restrict__ edge_attr,
    const int* __restrict__ esrc, const int* __restrict__ etgt,
    const uint4* __restrict__ Wt,
    const float* __restrict__ bfp, const float* __restrict__ bsp,
    float* __restrict__ agg)
{
    __shared__ unsigned short sW[WSLAB];       // 36864 B
    __shared__ unsigned short sZ[BE * WROW];   // 18432 B
    __shared__ int sSrc[BE];
    __shared__ int sTgt[BE];

    const int tid  = threadIdx.x;
    const int lane = tid & 63;
    const int w    = tid >> 6;
    const int e0   = blockIdx.x * BE;

    // W row this thread stages (row n = tid), Z row zm + fp32 offset zk
    const int zm = tid >> 1;          // 0..127
    const int zk = (tid & 1) * 32;    // 0 or 32

    if (tid < BE) {
        sSrc[tid] = (e0 + tid < N_EDGES) ? esrc[e0 + tid] : 0;
    } else {
        int m = tid - BE;
        sTgt[m] = (e0 + m < N_EDGES) ? etgt[e0 + m] : 0;
    }

    // ---- preload kt=0 W into regs (no LDS dep) ----
    uint4 wreg[8];
#pragma unroll
    for (int i = 0; i < 8; i++) wreg[i] = Wt[(size_t)i * 256 + tid];

    __syncthreads();   // sSrc/sTgt visible

    // ---- preload kt=0 Z into regs ----
    float4 zreg[8];
    {
        const float* zsrc = x + (size_t)sSrc[zm] * D;   // kt=0: x[src], half 0
#pragma unroll
        for (int i = 0; i < 8; i++) zreg[i] = *(const float4*)(zsrc + zk + i * 4);
    }

    floatx4 acc[8][4];
#pragma unroll
    for (int mt = 0; mt < 8; mt++)
#pragma unroll
        for (int nt = 0; nt < 4; nt++) {
            floatx4 z = {0.f, 0.f, 0.f, 0.f};
            acc[mt][nt] = z;
        }

#pragma unroll
    for (int kt = 0; kt < NKT; kt++) {
        // ---- ds_write staged regs (prev MFMA finished at trailing barrier) ----
        {
            unsigned short* dw = sW + tid * WROW;   // row n = tid, 144 B used
#pragma unroll
            for (int i = 0; i < 8; i++) *(uint4*)(dw + i * 8) = wreg[i];

            uint32_t u[16];
#pragma unroll
            for (int i = 0; i < 8; i++) {
                u[2 * i]     = pack_bf16(zreg[i].x, zreg[i].y);
                u[2 * i + 1] = pack_bf16(zreg[i].z, zreg[i].w);
            }
            unsigned short* dz = sZ + zm * WROW + zk;
#pragma unroll
            for (int i = 0; i < 4; i++) {
                uint4 v; v.x = u[4 * i]; v.y = u[4 * i + 1];
                v.z = u[4 * i + 2]; v.w = u[4 * i + 3];
                *(uint4*)(dz + i * 8) = v;
            }
        }
        __syncthreads();

        // ---- prefetch kt+1 into regs: overlaps the MFMA section below ----
        if (kt < NKT - 1) {
            const int kn = kt + 1;
#pragma unroll
            for (int i = 0; i < 8; i++)
                wreg[i] = Wt[(size_t)(kn * 8 + i) * 256 + tid];
            const float* zsrc;
            if (kn < 2)      zsrc = x + (size_t)sSrc[zm] * D + (kn & 1) * 64;
            else if (kn < 4) zsrc = x + (size_t)sTgt[zm] * D + (kn & 1) * 64;
            else {
                int eg = e0 + zm;
                zsrc = edge_attr + (size_t)(eg < N_EDGES ? eg : 0) * D + (kn & 1) * 64;
            }
#pragma unroll
            for (int i = 0; i < 8; i++) zreg[i] = *(const float4*)(zsrc + zk + i * 4);
        }

        // ---- MFMA: 2 k-steps of 32; 8 m-tiles x (2 f + 2 s) n-tiles ----
#pragma unroll
        for (int ks = 0; ks < 2; ks++) {
            const int kb = ks * 32 + (lane >> 4) * 8;   // bf16 offset in row
            bf16x8 bfr[4];
#pragma unroll
            for (int nt = 0; nt < 4; nt++) {
                int n = (nt < 2) ? (w * 32 + nt * 16 + (lane & 15))
                                 : (128 + w * 32 + (nt - 2) * 16 + (lane & 15));
                bfr[nt] = *(const bf16x8*)(sW + n * WROW + kb);
            }
#pragma unroll
            for (int mt = 0; mt < 8; mt++) {
                bf16x8 afr = *(const bf16x8*)(sZ + (mt * 16 + (lane & 15)) * WROW + kb);
#pragma unroll
                for (int nt = 0; nt < 4; nt++)
                    acc[mt][nt] = __builtin_amdgcn_mfma_f32_16x16x32_bf16(
                        afr, bfr[nt], acc[mt][nt], 0, 0, 0);
            }
        }
        __syncthreads();   // drains prefetch loads (had full MFMA section) + LDS reuse
    }

    // ---- epilogue: bias + gate (native exp/log/rcp) + atomic scatter ----
#pragma unroll
    for (int nt = 0; nt < 2; nt++) {
        const int col = w * 32 + nt * 16 + (lane & 15);
        const float bF = bfp[col];
        const float bS = bsp[col];
#pragma unroll
        for (int mt = 0; mt < 8; mt++) {
#pragma unroll
            for (int r = 0; r < 4; r++) {
                int mm = mt * 16 + (lane >> 4) * 4 + r;
                int eg = e0 + mm;
                if (eg >= N_EDGES) continue;
                float f = acc[mt][nt][r] + bF;
                float s = acc[mt][nt + 2][r] + bS;
                float msg = fast_sigmoid(f) * fast_softplus(s);
                atomicAdd(agg + (size_t)sSrc[mm] * D + col, msg);
            }
        }
    }
}

// Column sums/sumsq over agg [N,128] -> stats[0..127]=sum, [128..255]=sumsq.
// float4 loads, LDS reduce over 8 row-groups, then scalar atomics.
#define STATS_BLOCKS 128
__global__ __launch_bounds__(256) void bn_stats_kernel(
    const float* __restrict__ agg, float* __restrict__ stats)
{
    __shared__ float4 redS[256];
    __shared__ float4 redQ[256];
    const int c4 = threadIdx.x & 31;   // float4 column group
    const int rg = threadIdx.x >> 5;   // row group 0..7
    const int rows = (N_NODES + STATS_BLOCKS - 1) / STATS_BLOCKS;
    const int r0 = blockIdx.x * rows;
    const int r1 = min(r0 + rows, N_NODES);
    const float4* a4 = (const float4*)agg;

    float4 s = {0, 0, 0, 0}, q = {0, 0, 0, 0};
    for (int r = r0 + rg; r < r1; r += 8) {
        float4 v = a4[(size_t)r * 32 + c4];
        s.x += v.x; s.y += v.y; s.z += v.z; s.w += v.w;
        q.x += v.x * v.x; q.y += v.y * v.y; q.z += v.z * v.z; q.w += v.w * v.w;
    }
    redS[threadIdx.x] = s;
    redQ[threadIdx.x] = q;
    __syncthreads();
    if (rg == 0) {
#pragma unroll
        for (int j = 1; j < 8; j++) {
            float4 ts = redS[c4 + j * 32], tq = redQ[c4 + j * 32];
            s.x += ts.x; s.y += ts.y; s.z += ts.z; s.w += ts.w;
            q.x += tq.x; q.y += tq.y; q.z += tq.z; q.w += tq.w;
        }
        atomicAdd(&stats[c4 * 4 + 0], s.x);
        atomicAdd(&stats[c4 * 4 + 1], s.y);
        atomicAdd(&stats[c4 * 4 + 2], s.z);
        atomicAdd(&stats[c4 * 4 + 3], s.w);
        atomicAdd(&stats[D + c4 * 4 + 0], q.x);
        atomicAdd(&stats[D + c4 * 4 + 1], q.y);
        atomicAdd(&stats[D + c4 * 4 + 2], q.z);
        atomicAdd(&stats[D + c4 * 4 + 3], q.w);
    }
}

__global__ __launch_bounds__(256) void bn_final_kernel(
    const float* __restrict__ x, const float* __restrict__ agg,
    const float* __restrict__ stats,
    const float* __restrict__ gamma, const float* __restrict__ beta,
    float* __restrict__ out)
{
    const int idx = blockIdx.x * blockDim.x + threadIdx.x;  // float4 index
    const int total4 = N_NODES * D / 4;
    if (idx >= total4) return;
    const int c4 = idx & (D / 4 - 1);
    const float inv_n = 1.0f / (float)N_NODES;

    float4 sm = *(const float4*)&stats[c4 * 4];
    float4 sq = *(const float4*)&stats[D + c4 * 4];
    float4 g  = *(const float4*)&gamma[c4 * 4];
    float4 b  = *(const float4*)&beta[c4 * 4];
    float4 xv = ((const float4*)x)[idx];
    float4 av = ((const float4*)agg)[idx];

    float4 o;
    {
        float mean = sm.x * inv_n, var = sq.x * inv_n - mean * mean;
        float is = rsqrtf(var + 1e-5f) * g.x;
        o.x = fast_softplus(xv.x + (av.x - mean) * is + b.x);
    }
    {
        float mean = sm.y * inv_n, var = sq.y * inv_n - mean * mean;
        float is = rsqrtf(var + 1e-5f) * g.y;
        o.y = fast_softplus(xv.y + (av.y - mean) * is + b.y);
    }
    {
        float mean = sm.z * inv_n, var = sq.z * inv_n - mean * mean;
        float is = rsqrtf(var + 1e-5f) * g.z;
        o.z = fast_softplus(xv.z + (av.z - mean) * is + b.z);
    }
    {
        float mean = sm.w * inv_n, var = sq.w * inv_n - mean * mean;
        float is = rsqrtf(var + 1e-5f) * g.w;
        o.w = fast_softplus(xv.w + (av.w - mean) * is + b.w);
    }
    ((float4*)out)[idx] = o;
}

extern "C" void kernel_launch(void* const* d_in, const int* in_sizes, int n_in,
                              void* d_out, int out_size, void* d_ws, size_t ws_size,
                              hipStream_t stream) {
    const float* x         = (const float*)d_in[0];
    const float* edge_attr = (const float*)d_in[1];
    const int*   esrc      = (const int*)d_in[2];
    const int*   etgt      = (const int*)d_in[3];
    const float* Wf        = (const float*)d_in[4];
    const float* bf_       = (const float*)d_in[5];
    const float* Ws        = (const float*)d_in[6];
    const float* bs_       = (const float*)d_in[7];
    const float* gamma     = (const float*)d_in[8];
    const float* beta      = (const float*)d_in[9];
    float* out = (float*)d_out;

    float* agg   = (float*)d_ws;                     // 25,600,000 B
    float* stats = agg + (size_t)N_NODES * D;        // 1024 B
    uint4* Wt    = (uint4*)(stats + 2 * D);          // 196,608 B

    // zero agg + stats (ws poisoned 0xAA before every call)
    hipMemsetAsync(d_ws, 0, ((size_t)N_NODES * D + 2 * D) * sizeof(float), stream);

    wt_prepass<<<48, 256, 0, stream>>>(Wf, Ws, Wt);
    edge_msg_mfma<<<(N_EDGES + BE - 1) / BE, 256, 0, stream>>>(
        x, edge_attr, esrc, etgt, Wt, bf_, bs_, agg);
    bn_stats_kernel<<<STATS_BLOCKS, 256, 0, stream>>>(agg, stats);
    bn_final_kernel<<<(N_NODES * D / 4 + 255) / 256, 256, 0, stream>>>(
        x, agg, stats, gamma, beta, out);
}

// Round 5
// 784.320 us; speedup vs baseline: 1.1321x; 1.1321x over previous
//
#include <hip/hip_runtime.h>
#include <math.h>
#include <stdint.h>

#define N_NODES 50000
#define N_EDGES 500000
#define D 128
#define BE 64          // edges per block (proven R3 tile)
#define NKT 6          // 384 / 64 K-tiles
#define WROW 72        // padded LDS/global row stride in bf16 (64 real + 8 pad)
#define WSLAB (256 * WROW)   // 36,864 B per kt slab (bytes = WSLAB*2? no: shorts)
#define LOG2E 1.4426950408889634f
#define LN2   0.6931471805599453f

typedef __attribute__((ext_vector_type(8))) short bf16x8;
typedef __attribute__((ext_vector_type(4))) float floatx4;

__device__ __forceinline__ float fast_sigmoid(float v) {
    return __builtin_amdgcn_rcpf(1.0f + __builtin_amdgcn_exp2f(-v * LOG2E));
}
__device__ __forceinline__ float fast_softplus(float v) {
    float t = __builtin_amdgcn_exp2f(-fabsf(v) * LOG2E);
    return fmaxf(v, 0.0f) + __builtin_amdgcn_logf(1.0f + t) * LN2;
}
__device__ __forceinline__ uint32_t pack_bf16(float a, float b) {
    union { float f; uint32_t u; } ca, cb; ca.f = a; cb.f = b;
    return __builtin_amdgcn_perm(cb.u + 0x8000u, ca.u + 0x8000u, 0x07060302);
}
__device__ __forceinline__ unsigned short f2bf(float f) {
    union { float f; uint32_t u; } c; c.f = f;
    return (unsigned short)((c.u + 0x8000u) >> 16);
}

// Wt padded layout: [kt][n][72 bf16] (row = 64 k-values + 8 pad, pad never
// read). Block (kt,i) handles k-chunk i (8 k's) for all 256 n: 8 coalesced
// row reads per thread-own n, one uint4 store.
__global__ __launch_bounds__(256) void wt_prepass(
    const float* __restrict__ Wf, const float* __restrict__ Ws,
    unsigned short* __restrict__ Wt)
{
    const int kt = blockIdx.x >> 3;
    const int i  = blockIdx.x & 7;
    const int n  = threadIdx.x;
    const float* src = (n < 128) ? (Wf + n) : (Ws + (n - 128));
    const int k0 = kt * 64 + i * 8;
    uint32_t u[4];
#pragma unroll
    for (int j = 0; j < 4; j++) {
        float a = src[(size_t)(k0 + 2 * j) * D];
        float b = src[(size_t)(k0 + 2 * j + 1) * D];
        u[j] = pack_bf16(a, b);
    }
    uint4 v; v.x = u[0]; v.y = u[1]; v.z = u[2]; v.w = u[3];
    *(uint4*)(Wt + (size_t)(kt * 256 + n) * WROW + i * 8) = v;
}

// R3-proven core: 64 edges x 256 outputs, K=384, bf16 MFMA 16x16x32,
// global_load_lds W staging. Epilogue: mode1 = plain bf16 stores to msgs
// (scatter deferred to CSR gather); mode0 = atomic fallback.
__global__ __launch_bounds__(256) void edge_msg_mfma(
    const float* __restrict__ x, const float* __restrict__ edge_attr,
    const int* __restrict__ esrc, const int* __restrict__ etgt,
    const unsigned short* __restrict__ Wt,
    const float* __restrict__ bfp, const float* __restrict__ bsp,
    float* __restrict__ agg, unsigned short* __restrict__ msgs, int mode)
{
    __shared__ unsigned short sW[WSLAB];       // 36864 shorts? no: 256*72 = 18432 shorts = 36864 B
    __shared__ unsigned short sZ[BE * WROW];   // 9216 B
    __shared__ int sSrc[BE];
    __shared__ int sTgt[BE];

    const int tid  = threadIdx.x;
    const int lane = tid & 63;
    const int w    = tid >> 6;
    const int e0   = blockIdx.x * BE;

    if (tid < BE) {
        sSrc[tid] = (e0 + tid < N_EDGES) ? esrc[e0 + tid] : 0;
    } else if (tid < 2 * BE) {
        int m = tid - BE;
        sTgt[m] = (e0 + m < N_EDGES) ? etgt[e0 + m] : 0;
    }
    __syncthreads();

    floatx4 acc[4][4];
#pragma unroll
    for (int mt = 0; mt < 4; mt++)
#pragma unroll
        for (int nt = 0; nt < 4; nt++) {
            floatx4 z = {0.f, 0.f, 0.f, 0.f};
            acc[mt][nt] = z;
        }

    const int zm = tid >> 2;         // edge row staged by this thread
    const int zk = (tid & 3) * 16;   // fp32 element offset in the 64-k tile

#pragma unroll 1
    for (int kt = 0; kt < NKT; kt++) {
        // ---- stage W slab via async global->LDS (16B/lane, verbatim) ----
        {
            const char* gbase = (const char*)Wt + (size_t)kt * 36864 + w * 9216 + lane * 16;
            char* lbase = (char*)sW + w * 9216;   // wave-uniform LDS base
#pragma unroll
            for (int i = 0; i < 9; i++) {
                __builtin_amdgcn_global_load_lds(
                    (const __attribute__((address_space(1))) void*)(gbase + i * 1024),
                    (__attribute__((address_space(3))) void*)(lbase + i * 1024),
                    16, 0, 0);
            }
        }
        // ---- stage Z tile: gather fp32, pack bf16 (v_perm), ds_write ----
        {
            const float* zsrc;
            int half = (kt & 1) * 64;
            if (kt < 2)      zsrc = x + (size_t)sSrc[zm] * D + half;
            else if (kt < 4) zsrc = x + (size_t)sTgt[zm] * D + half;
            else {
                int eg = e0 + zm;
                zsrc = edge_attr + (size_t)(eg < N_EDGES ? eg : 0) * D + half;
            }
            float4 f0 = *(const float4*)(zsrc + zk);
            float4 f1 = *(const float4*)(zsrc + zk + 4);
            float4 f2 = *(const float4*)(zsrc + zk + 8);
            float4 f3 = *(const float4*)(zsrc + zk + 12);
            uint4 lo, hi;
            lo.x = pack_bf16(f0.x, f0.y); lo.y = pack_bf16(f0.z, f0.w);
            lo.z = pack_bf16(f1.x, f1.y); lo.w = pack_bf16(f1.z, f1.w);
            hi.x = pack_bf16(f2.x, f2.y); hi.y = pack_bf16(f2.z, f2.w);
            hi.z = pack_bf16(f3.x, f3.y); hi.w = pack_bf16(f3.z, f3.w);
            uint32_t* dz = (uint32_t*)(sZ + (size_t)zm * WROW) + (zk >> 1);
            *(uint4*)(dz)     = lo;
            *(uint4*)(dz + 4) = hi;
        }
        __syncthreads();

        // ---- MFMA: 2 k-steps of 32; 4 m-tiles x (2 f + 2 s) n-tiles ----
#pragma unroll
        for (int ks = 0; ks < 2; ks++) {
            const int kb = ks * 32 + (lane >> 4) * 8;
            bf16x8 afr[4];
#pragma unroll
            for (int mt = 0; mt < 4; mt++)
                afr[mt] = *(const bf16x8*)(sZ + (mt * 16 + (lane & 15)) * WROW + kb);
            bf16x8 bfr[4];
#pragma unroll
            for (int nt = 0; nt < 4; nt++) {
                int n = (nt < 2) ? (w * 32 + nt * 16 + (lane & 15))
                                 : (128 + w * 32 + (nt - 2) * 16 + (lane & 15));
                bfr[nt] = *(const bf16x8*)(sW + n * WROW + kb);
            }
#pragma unroll
            for (int mt = 0; mt < 4; mt++)
#pragma unroll
                for (int nt = 0; nt < 4; nt++)
                    acc[mt][nt] = __builtin_amdgcn_mfma_f32_16x16x32_bf16(
                        afr[mt], bfr[nt], acc[mt][nt], 0, 0, 0);
        }
        __syncthreads();
    }

    // ---- epilogue: bias + gate; store bf16 msg (mode1) or atomic (mode0) ----
#pragma unroll
    for (int nt = 0; nt < 2; nt++) {
        const int col = w * 32 + nt * 16 + (lane & 15);
        const float bF = bfp[col];
        const float bS = bsp[col];
#pragma unroll
        for (int mt = 0; mt < 4; mt++) {
#pragma unroll
            for (int r = 0; r < 4; r++) {
                int mm = mt * 16 + (lane >> 4) * 4 + r;
                int eg = e0 + mm;
                if (eg >= N_EDGES) continue;
                float f = acc[mt][nt][r] + bF;
                float s = acc[mt][nt + 2][r] + bS;
                float msg = fast_sigmoid(f) * fast_softplus(s);
                if (mode) {
                    msgs[(size_t)eg * D + col] = f2bf(msg);
                } else {
                    atomicAdd(agg + (size_t)sSrc[mm] * D + col, msg);
                }
            }
        }
    }
}

// ---- CSR build ----
__global__ __launch_bounds__(512) void count_kernel(
    const int* __restrict__ esrc, int* __restrict__ cnt)
{
    int e = blockIdx.x * 512 + threadIdx.x;
    if (e < N_EDGES) atomicAdd(&cnt[esrc[e]], 1);
}

// single-block exclusive scan of cnt[50000] -> ofs
__global__ __launch_bounds__(1024) void scan_kernel(
    const int* __restrict__ cnt, int* __restrict__ ofs)
{
    __shared__ int part[1024];
    const int t = threadIdx.x;
    const int CH = (N_NODES + 1023) / 1024;   // 49
    const int i0 = t * CH;
    int s = 0;
    for (int j = 0; j < CH; j++) {
        int i = i0 + j;
        if (i < N_NODES) s += cnt[i];
    }
    part[t] = s;
    __syncthreads();
    for (int off = 1; off < 1024; off <<= 1) {
        int v = (t >= off) ? part[t - off] : 0;
        __syncthreads();
        part[t] += v;
        __syncthreads();
    }
    int running = part[t] - s;   // exclusive base of this chunk
    for (int j = 0; j < CH; j++) {
        int i = i0 + j;
        if (i < N_NODES) { ofs[i] = running; running += cnt[i]; }
    }
}

__global__ __launch_bounds__(512) void fill_kernel(
    const int* __restrict__ esrc, int* __restrict__ ofs, int* __restrict__ eidx)
{
    int e = blockIdx.x * 512 + threadIdx.x;
    if (e < N_EDGES) {
        int slot = atomicAdd(&ofs[esrc[e]], 1);
        eidx[slot] = e;
    }
}

// one wave per node: fp32-accumulate its edges' bf16 msg rows, write agg row.
__global__ __launch_bounds__(512) void gather_kernel(
    const unsigned short* __restrict__ msgs, const int* __restrict__ eidx,
    const int* __restrict__ cnt, const int* __restrict__ ofs,
    float* __restrict__ agg)
{
    const int lane = threadIdx.x & 63;
    const int w    = threadIdx.x >> 6;
    const int n    = blockIdx.x * 8 + w;
    if (n >= N_NODES) return;
    const int deg  = cnt[n];
    const int base = ofs[n] - deg;   // ofs was advanced by fill_kernel
    float a0 = 0.0f, a1 = 0.0f;
    for (int j = 0; j < deg; j++) {
        int id = eidx[base + j];
        uint32_t p = *(const uint32_t*)(msgs + (size_t)id * D + 2 * lane);
        union { uint32_t u; float f; } c0, c1;
        c0.u = p << 16;
        c1.u = p & 0xFFFF0000u;
        a0 += c0.f; a1 += c1.f;
    }
    float2 o; o.x = a0; o.y = a1;
    *(float2*)(agg + (size_t)n * D + 2 * lane) = o;
}

// Column sums/sumsq over agg [N,128] -> stats[0..127]=sum, [128..255]=sumsq.
#define STATS_BLOCKS 128
__global__ __launch_bounds__(256) void bn_stats_kernel(
    const float* __restrict__ agg, float* __restrict__ stats)
{
    __shared__ float4 redS[256];
    __shared__ float4 redQ[256];
    const int c4 = threadIdx.x & 31;
    const int rg = threadIdx.x >> 5;
    const int rows = (N_NODES + STATS_BLOCKS - 1) / STATS_BLOCKS;
    const int r0 = blockIdx.x * rows;
    const int r1 = min(r0 + rows, N_NODES);
    const float4* a4 = (const float4*)agg;

    float4 s = {0, 0, 0, 0}, q = {0, 0, 0, 0};
    for (int r = r0 + rg; r < r1; r += 8) {
        float4 v = a4[(size_t)r * 32 + c4];
        s.x += v.x; s.y += v.y; s.z += v.z; s.w += v.w;
        q.x += v.x * v.x; q.y += v.y * v.y; q.z += v.z * v.z; q.w += v.w * v.w;
    }
    redS[threadIdx.x] = s;
    redQ[threadIdx.x] = q;
    __syncthreads();
    if (rg == 0) {
#pragma unroll
        for (int j = 1; j < 8; j++) {
            float4 ts = redS[c4 + j * 32], tq = redQ[c4 + j * 32];
            s.x += ts.x; s.y += ts.y; s.z += ts.z; s.w += ts.w;
            q.x += tq.x; q.y += tq.y; q.z += tq.z; q.w += tq.w;
        }
        atomicAdd(&stats[c4 * 4 + 0], s.x);
        atomicAdd(&stats[c4 * 4 + 1], s.y);
        atomicAdd(&stats[c4 * 4 + 2], s.z);
        atomicAdd(&stats[c4 * 4 + 3], s.w);
        atomicAdd(&stats[D + c4 * 4 + 0], q.x);
        atomicAdd(&stats[D + c4 * 4 + 1], q.y);
        atomicAdd(&stats[D + c4 * 4 + 2], q.z);
        atomicAdd(&stats[D + c4 * 4 + 3], q.w);
    }
}

__global__ __launch_bounds__(256) void bn_final_kernel(
    const float* __restrict__ x, const float* __restrict__ agg,
    const float* __restrict__ stats,
    const float* __restrict__ gamma, const float* __restrict__ beta,
    float* __restrict__ out)
{
    const int idx = blockIdx.x * blockDim.x + threadIdx.x;
    const int total4 = N_NODES * D / 4;
    if (idx >= total4) return;
    const int c4 = idx & (D / 4 - 1);
    const float inv_n = 1.0f / (float)N_NODES;

    float4 sm = *(const float4*)&stats[c4 * 4];
    float4 sq = *(const float4*)&stats[D + c4 * 4];
    float4 g  = *(const float4*)&gamma[c4 * 4];
    float4 b  = *(const float4*)&beta[c4 * 4];
    float4 xv = ((const float4*)x)[idx];
    float4 av = ((const float4*)agg)[idx];

    float4 o;
    {
        float mean = sm.x * inv_n, var = sq.x * inv_n - mean * mean;
        float is = rsqrtf(var + 1e-5f) * g.x;
        o.x = fast_softplus(xv.x + (av.x - mean) * is + b.x);
    }
    {
        float mean = sm.y * inv_n, var = sq.y * inv_n - mean * mean;
        float is = rsqrtf(var + 1e-5f) * g.y;
        o.y = fast_softplus(xv.y + (av.y - mean) * is + b.y);
    }
    {
        float mean = sm.z * inv_n, var = sq.z * inv_n - mean * mean;
        float is = rsqrtf(var + 1e-5f) * g.z;
        o.z = fast_softplus(xv.z + (av.z - mean) * is + b.z);
    }
    {
        float mean = sm.w * inv_n, var = sq.w * inv_n - mean * mean;
        float is = rsqrtf(var + 1e-5f) * g.w;
        o.w = fast_softplus(xv.w + (av.w - mean) * is + b.w);
    }
    ((float4*)out)[idx] = o;
}

extern "C" void kernel_launch(void* const* d_in, const int* in_sizes, int n_in,
                              void* d_out, int out_size, void* d_ws, size_t ws_size,
                              hipStream_t stream) {
    const float* x         = (const float*)d_in[0];
    const float* edge_attr = (const float*)d_in[1];
    const int*   esrc      = (const int*)d_in[2];
    const int*   etgt      = (const int*)d_in[3];
    const float* Wf        = (const float*)d_in[4];
    const float* bf_       = (const float*)d_in[5];
    const float* Ws        = (const float*)d_in[6];
    const float* bs_       = (const float*)d_in[7];
    const float* gamma     = (const float*)d_in[8];
    const float* beta      = (const float*)d_in[9];
    float* out = (float*)d_out;

    // ws layout (16B-aligned sections):
    float* agg   = (float*)d_ws;                          // 25,600,000 B
    float* stats = agg + (size_t)N_NODES * D;             //      1,024 B
    int*   cnt   = (int*)(stats + 2 * D);                 //    200,000 B
    int*   ofs   = cnt + N_NODES;                         //    200,000 B
    unsigned short* Wt = (unsigned short*)(ofs + N_NODES);//    221,184 B
    int*   eidx  = (int*)((char*)Wt + 221184);            //  2,000,000 B
    unsigned short* msgs = (unsigned short*)(eidx + N_EDGES); // 128,000,000 B
    const size_t NEED = 25600000ULL + 1024 + 400000 + 221184 + 2000000 + 128000000ULL;
    const int mode = (ws_size >= NEED) ? 1 : 0;

    wt_prepass<<<48, 256, 0, stream>>>(Wf, Ws, Wt);
    if (mode) {
        // zero stats + cnt only (agg fully written by gather)
        hipMemsetAsync(stats, 0, 1024 + 200000, stream);
        edge_msg_mfma<<<(N_EDGES + BE - 1) / BE, 256, 0, stream>>>(
            x, edge_attr, esrc, etgt, Wt, bf_, bs_, agg, msgs, 1);
        count_kernel<<<(N_EDGES + 511) / 512, 512, 0, stream>>>(esrc, cnt);
        scan_kernel<<<1, 1024, 0, stream>>>(cnt, ofs);
        fill_kernel<<<(N_EDGES + 511) / 512, 512, 0, stream>>>(esrc, ofs, eidx);
        gather_kernel<<<(N_NODES + 7) / 8, 512, 0, stream>>>(msgs, eidx, cnt, ofs, agg);
    } else {
        hipMemsetAsync(d_ws, 0, ((size_t)N_NODES * D + 2 * D) * sizeof(float), stream);
        edge_msg_mfma<<<(N_EDGES + BE - 1) / BE, 256, 0, stream>>>(
            x, edge_attr, esrc, etgt, Wt, bf_, bs_, agg, msgs, 0);
    }
    bn_stats_kernel<<<STATS_BLOCKS, 256, 0, stream>>>(agg, stats);
    bn_final_kernel<<<(N_NODES * D / 4 + 255) / 256, 256, 0, stream>>>(
        x, agg, stats, gamma, beta, out);
}

// Round 6
// 660.142 us; speedup vs baseline: 1.3451x; 1.1881x over previous
//
#include <hip/hip_runtime.h>
#include <math.h>
#include <stdint.h>

#define N_NODES 50000
#define N_EDGES 500000
#define D 128
#define BE 64          // edges per block (proven tile)
#define NKT 6          // 384 / 64 K-tiles
#define WROW 72        // padded LDS/global row stride in bf16 (64 real + 8 pad)
#define WSLAB (256 * WROW)   // shorts per kt slab (36,864 B)
#define MROW 136       // msg repack LDS row stride in bf16 (16B-aligned rows)
#define LOG2E 1.4426950408889634f
#define LN2   0.6931471805599453f

typedef __attribute__((ext_vector_type(8))) short bf16x8;
typedef __attribute__((ext_vector_type(4))) float floatx4;

__device__ __forceinline__ float fast_sigmoid(float v) {
    return __builtin_amdgcn_rcpf(1.0f + __builtin_amdgcn_exp2f(-v * LOG2E));
}
__device__ __forceinline__ float fast_softplus(float v) {
    float t = __builtin_amdgcn_exp2f(-fabsf(v) * LOG2E);
    return fmaxf(v, 0.0f) + __builtin_amdgcn_logf(1.0f + t) * LN2;
}
__device__ __forceinline__ uint32_t pack_bf16(float a, float b) {
    union { float f; uint32_t u; } ca, cb; ca.f = a; cb.f = b;
    return __builtin_amdgcn_perm(cb.u + 0x8000u, ca.u + 0x8000u, 0x07060302);
}
__device__ __forceinline__ unsigned short f2bf(float f) {
    union { float f; uint32_t u; } c; c.f = f;
    return (unsigned short)((c.u + 0x8000u) >> 16);
}

// Wt padded layout: [kt][n][72 bf16]; block (kt,i) converts k-chunk i for all n.
__global__ __launch_bounds__(256) void wt_prepass(
    const float* __restrict__ Wf, const float* __restrict__ Ws,
    unsigned short* __restrict__ Wt)
{
    const int kt = blockIdx.x >> 3;
    const int i  = blockIdx.x & 7;
    const int n  = threadIdx.x;
    const float* src = (n < 128) ? (Wf + n) : (Ws + (n - 128));
    const int k0 = kt * 64 + i * 8;
    uint32_t u[4];
#pragma unroll
    for (int j = 0; j < 4; j++) {
        float a = src[(size_t)(k0 + 2 * j) * D];
        float b = src[(size_t)(k0 + 2 * j + 1) * D];
        u[j] = pack_bf16(a, b);
    }
    uint4 v; v.x = u[0]; v.y = u[1]; v.z = u[2]; v.w = u[3];
    *(uint4*)(Wt + (size_t)(kt * 256 + n) * WROW + i * 8) = v;
}

// 64 edges x 256 outputs, K=384, bf16 MFMA 16x16x32, global_load_lds W staging.
// mode1: LDS-repacked coalesced bf16 msg stores + fused degree count.
// mode0: atomicAdd fallback.
__global__ __launch_bounds__(256) void edge_msg_mfma(
    const float* __restrict__ x, const float* __restrict__ edge_attr,
    const int* __restrict__ esrc, const int* __restrict__ etgt,
    const unsigned short* __restrict__ Wt,
    const float* __restrict__ bfp, const float* __restrict__ bsp,
    float* __restrict__ agg, unsigned short* __restrict__ msgs,
    int* __restrict__ cnt, int mode)
{
    __shared__ unsigned short sW[WSLAB];       // 36,864 B (reused as msg tile)
    __shared__ unsigned short sZ[BE * WROW];   //  9,216 B
    __shared__ int sSrc[BE];
    __shared__ int sTgt[BE];

    const int tid  = threadIdx.x;
    const int lane = tid & 63;
    const int w    = tid >> 6;
    const int e0   = blockIdx.x * BE;

    if (tid < BE) {
        sSrc[tid] = (e0 + tid < N_EDGES) ? esrc[e0 + tid] : 0;
    } else if (tid < 2 * BE) {
        int m = tid - BE;
        sTgt[m] = (e0 + m < N_EDGES) ? etgt[e0 + m] : 0;
    }
    __syncthreads();

    floatx4 acc[4][4];
#pragma unroll
    for (int mt = 0; mt < 4; mt++)
#pragma unroll
        for (int nt = 0; nt < 4; nt++) {
            floatx4 z = {0.f, 0.f, 0.f, 0.f};
            acc[mt][nt] = z;
        }

    const int zm = tid >> 2;
    const int zk = (tid & 3) * 16;

#pragma unroll 1
    for (int kt = 0; kt < NKT; kt++) {
        {
            const char* gbase = (const char*)Wt + (size_t)kt * 36864 + w * 9216 + lane * 16;
            char* lbase = (char*)sW + w * 9216;
#pragma unroll
            for (int i = 0; i < 9; i++) {
                __builtin_amdgcn_global_load_lds(
                    (const __attribute__((address_space(1))) void*)(gbase + i * 1024),
                    (__attribute__((address_space(3))) void*)(lbase + i * 1024),
                    16, 0, 0);
            }
        }
        {
            const float* zsrc;
            int half = (kt & 1) * 64;
            if (kt < 2)      zsrc = x + (size_t)sSrc[zm] * D + half;
            else if (kt < 4) zsrc = x + (size_t)sTgt[zm] * D + half;
            else {
                int eg = e0 + zm;
                zsrc = edge_attr + (size_t)(eg < N_EDGES ? eg : 0) * D + half;
            }
            float4 f0 = *(const float4*)(zsrc + zk);
            float4 f1 = *(const float4*)(zsrc + zk + 4);
            float4 f2 = *(const float4*)(zsrc + zk + 8);
            float4 f3 = *(const float4*)(zsrc + zk + 12);
            uint4 lo, hi;
            lo.x = pack_bf16(f0.x, f0.y); lo.y = pack_bf16(f0.z, f0.w);
            lo.z = pack_bf16(f1.x, f1.y); lo.w = pack_bf16(f1.z, f1.w);
            hi.x = pack_bf16(f2.x, f2.y); hi.y = pack_bf16(f2.z, f2.w);
            hi.z = pack_bf16(f3.x, f3.y); hi.w = pack_bf16(f3.z, f3.w);
            uint32_t* dz = (uint32_t*)(sZ + (size_t)zm * WROW) + (zk >> 1);
            *(uint4*)(dz)     = lo;
            *(uint4*)(dz + 4) = hi;
        }
        __syncthreads();

#pragma unroll
        for (int ks = 0; ks < 2; ks++) {
            const int kb = ks * 32 + (lane >> 4) * 8;
            bf16x8 afr[4];
#pragma unroll
            for (int mt = 0; mt < 4; mt++)
                afr[mt] = *(const bf16x8*)(sZ + (mt * 16 + (lane & 15)) * WROW + kb);
            bf16x8 bfr[4];
#pragma unroll
            for (int nt = 0; nt < 4; nt++) {
                int n = (nt < 2) ? (w * 32 + nt * 16 + (lane & 15))
                                 : (128 + w * 32 + (nt - 2) * 16 + (lane & 15));
                bfr[nt] = *(const bf16x8*)(sW + n * WROW + kb);
            }
#pragma unroll
            for (int mt = 0; mt < 4; mt++)
#pragma unroll
                for (int nt = 0; nt < 4; nt++)
                    acc[mt][nt] = __builtin_amdgcn_mfma_f32_16x16x32_bf16(
                        afr[mt], bfr[nt], acc[mt][nt], 0, 0, 0);
        }
        __syncthreads();
    }

    // ---- epilogue: bias + gate ----
    if (mode) {
        unsigned short* sM = sW;   // reuse: 64 x MROW bf16 tile
#pragma unroll
        for (int nt = 0; nt < 2; nt++) {
            const int col = w * 32 + nt * 16 + (lane & 15);
            const float bF = bfp[col];
            const float bS = bsp[col];
#pragma unroll
            for (int mt = 0; mt < 4; mt++) {
#pragma unroll
                for (int r = 0; r < 4; r++) {
                    int mm = mt * 16 + (lane >> 4) * 4 + r;
                    float f = acc[mt][nt][r] + bF;
                    float s = acc[mt][nt + 2][r] + bS;
                    sM[mm * MROW + col] = f2bf(fast_sigmoid(f) * fast_softplus(s));
                }
            }
        }
        __syncthreads();
        // linear re-read + fully coalesced store: thread t -> row t>>2, chunk t&3
        {
            const int r = tid >> 2;
            const int c = tid & 3;
            if (e0 + r < N_EDGES) {
                const uint4* sp = (const uint4*)(sM + r * MROW + c * 32);
                uint4 v0 = sp[0], v1 = sp[1], v2 = sp[2], v3 = sp[3];
                uint4* dp = (uint4*)(msgs + (size_t)(e0 + r) * D + c * 32);
                dp[0] = v0; dp[1] = v1; dp[2] = v2; dp[3] = v3;
            }
        }
        // fused degree count
        if (tid < BE && e0 + tid < N_EDGES) atomicAdd(&cnt[sSrc[tid]], 1);
    } else {
#pragma unroll
        for (int nt = 0; nt < 2; nt++) {
            const int col = w * 32 + nt * 16 + (lane & 15);
            const float bF = bfp[col];
            const float bS = bsp[col];
#pragma unroll
            for (int mt = 0; mt < 4; mt++) {
#pragma unroll
                for (int r = 0; r < 4; r++) {
                    int mm = mt * 16 + (lane >> 4) * 4 + r;
                    int eg = e0 + mm;
                    if (eg >= N_EDGES) continue;
                    float f = acc[mt][nt][r] + bF;
                    float s = acc[mt][nt + 2][r] + bS;
                    atomicAdd(agg + (size_t)sSrc[mm] * D + col,
                              fast_sigmoid(f) * fast_softplus(s));
                }
            }
        }
    }
}

// ---- CSR build: parallel scan (49 blocks x 1024), tiny top scan ----
__global__ __launch_bounds__(1024) void scan1_kernel(
    const int* __restrict__ cnt, int* __restrict__ ofs, int* __restrict__ bsum)
{
    __shared__ int sh[1024];
    const int t = threadIdx.x;
    const int n = blockIdx.x * 1024 + t;
    int c = (n < N_NODES) ? cnt[n] : 0;
    sh[t] = c;
    __syncthreads();
    for (int off = 1; off < 1024; off <<= 1) {
        int v = (t >= off) ? sh[t - off] : 0;
        __syncthreads();
        sh[t] += v;
        __syncthreads();
    }
    if (n < N_NODES) ofs[n] = sh[t] - c;      // block-local exclusive
    if (t == 1023) bsum[blockIdx.x] = sh[1023];
}

__global__ __launch_bounds__(64) void scan2_kernel(int* __restrict__ bsum)
{
    if (threadIdx.x == 0) {
        int v[49];
#pragma unroll
        for (int i = 0; i < 49; i++) v[i] = bsum[i];
        int run = 0;
#pragma unroll
        for (int i = 0; i < 49; i++) { bsum[i] = run; run += v[i]; }
    }
}

__global__ __launch_bounds__(512) void fill_kernel(
    const int* __restrict__ esrc, int* __restrict__ ofs,
    const int* __restrict__ bsum, int* __restrict__ eidx)
{
    int e = blockIdx.x * 512 + threadIdx.x;
    if (e < N_EDGES) {
        int s = esrc[e];
        int slot = atomicAdd(&ofs[s], 1) + bsum[s >> 10];
        eidx[slot] = e;
    }
}

// 2 nodes per block, 2 waves per node (even/odd edges), LDS combine.
__global__ __launch_bounds__(256) void gather_kernel(
    const unsigned short* __restrict__ msgs, const int* __restrict__ eidx,
    const int* __restrict__ cnt, const int* __restrict__ ofs,
    const int* __restrict__ bsum, float* __restrict__ agg)
{
    __shared__ float red[2][64][2];
    const int tid  = threadIdx.x;
    const int lane = tid & 63;
    const int w2   = (tid >> 6) & 1;
    const int h    = tid >> 7;
    const int n    = blockIdx.x * 2 + h;    // grid 25000, always < N_NODES
    const int deg  = cnt[n];
    const int base = bsum[n >> 10] + ofs[n] - deg;   // ofs advanced by fill
    float a0 = 0.0f, a1 = 0.0f;
    for (int j = w2; j < deg; j += 2) {
        int id = eidx[base + j];
        uint32_t p = *(const uint32_t*)(msgs + (size_t)id * D + 2 * lane);
        union { uint32_t u; float f; } c0, c1;
        c0.u = p << 16;
        c1.u = p & 0xFFFF0000u;
        a0 += c0.f; a1 += c1.f;
    }
    if (w2 == 1) { red[h][lane][0] = a0; red[h][lane][1] = a1; }
    __syncthreads();
    if (w2 == 0) {
        a0 += red[h][lane][0];
        a1 += red[h][lane][1];
        float2 o; o.x = a0; o.y = a1;
        *(float2*)(agg + (size_t)n * D + 2 * lane) = o;
    }
}

#define STATS_BLOCKS 128
__global__ __launch_bounds__(256) void bn_stats_kernel(
    const float* __restrict__ agg, float* __restrict__ stats)
{
    __shared__ float4 redS[256];
    __shared__ float4 redQ[256];
    const int c4 = threadIdx.x & 31;
    const int rg = threadIdx.x >> 5;
    const int rows = (N_NODES + STATS_BLOCKS - 1) / STATS_BLOCKS;
    const int r0 = blockIdx.x * rows;
    const int r1 = min(r0 + rows, N_NODES);
    const float4* a4 = (const float4*)agg;

    float4 s = {0, 0, 0, 0}, q = {0, 0, 0, 0};
    for (int r = r0 + rg; r < r1; r += 8) {
        float4 v = a4[(size_t)r * 32 + c4];
        s.x += v.x; s.y += v.y; s.z += v.z; s.w += v.w;
        q.x += v.x * v.x; q.y += v.y * v.y; q.z += v.z * v.z; q.w += v.w * v.w;
    }
    redS[threadIdx.x] = s;
    redQ[threadIdx.x] = q;
    __syncthreads();
    if (rg == 0) {
#pragma unroll
        for (int j = 1; j < 8; j++) {
            float4 ts = redS[c4 + j * 32], tq = redQ[c4 + j * 32];
            s.x += ts.x; s.y += ts.y; s.z += ts.z; s.w += ts.w;
            q.x += tq.x; q.y += tq.y; q.z += tq.z; q.w += tq.w;
        }
        atomicAdd(&stats[c4 * 4 + 0], s.x);
        atomicAdd(&stats[c4 * 4 + 1], s.y);
        atomicAdd(&stats[c4 * 4 + 2], s.z);
        atomicAdd(&stats[c4 * 4 + 3], s.w);
        atomicAdd(&stats[D + c4 * 4 + 0], q.x);
        atomicAdd(&stats[D + c4 * 4 + 1], q.y);
        atomicAdd(&stats[D + c4 * 4 + 2], q.z);
        atomicAdd(&stats[D + c4 * 4 + 3], q.w);
    }
}

__global__ __launch_bounds__(256) void bn_final_kernel(
    const float* __restrict__ x, const float* __restrict__ agg,
    const float* __restrict__ stats,
    const float* __restrict__ gamma, const float* __restrict__ beta,
    float* __restrict__ out)
{
    const int idx = blockIdx.x * blockDim.x + threadIdx.x;
    const int total4 = N_NODES * D / 4;
    if (idx >= total4) return;
    const int c4 = idx & (D / 4 - 1);
    const float inv_n = 1.0f / (float)N_NODES;

    float4 sm = *(const float4*)&stats[c4 * 4];
    float4 sq = *(const float4*)&stats[D + c4 * 4];
    float4 g  = *(const float4*)&gamma[c4 * 4];
    float4 b  = *(const float4*)&beta[c4 * 4];
    float4 xv = ((const float4*)x)[idx];
    float4 av = ((const float4*)agg)[idx];

    float4 o;
    {
        float mean = sm.x * inv_n, var = sq.x * inv_n - mean * mean;
        float is = rsqrtf(var + 1e-5f) * g.x;
        o.x = fast_softplus(xv.x + (av.x - mean) * is + b.x);
    }
    {
        float mean = sm.y * inv_n, var = sq.y * inv_n - mean * mean;
        float is = rsqrtf(var + 1e-5f) * g.y;
        o.y = fast_softplus(xv.y + (av.y - mean) * is + b.y);
    }
    {
        float mean = sm.z * inv_n, var = sq.z * inv_n - mean * mean;
        float is = rsqrtf(var + 1e-5f) * g.z;
        o.z = fast_softplus(xv.z + (av.z - mean) * is + b.z);
    }
    {
        float mean = sm.w * inv_n, var = sq.w * inv_n - mean * mean;
        float is = rsqrtf(var + 1e-5f) * g.w;
        o.w = fast_softplus(xv.w + (av.w - mean) * is + b.w);
    }
    ((float4*)out)[idx] = o;
}

extern "C" void kernel_launch(void* const* d_in, const int* in_sizes, int n_in,
                              void* d_out, int out_size, void* d_ws, size_t ws_size,
                              hipStream_t stream) {
    const float* x         = (const float*)d_in[0];
    const float* edge_attr = (const float*)d_in[1];
    const int*   esrc      = (const int*)d_in[2];
    const int*   etgt      = (const int*)d_in[3];
    const float* Wf        = (const float*)d_in[4];
    const float* bf_       = (const float*)d_in[5];
    const float* Ws        = (const float*)d_in[6];
    const float* bs_       = (const float*)d_in[7];
    const float* gamma     = (const float*)d_in[8];
    const float* beta      = (const float*)d_in[9];
    float* out = (float*)d_out;

    // ws layout (all sections 16B-aligned):
    float* agg   = (float*)d_ws;                           // 25,600,000 B
    float* stats = agg + (size_t)N_NODES * D;              //      1,024 B
    int*   cnt   = (int*)(stats + 2 * D);                  //    200,000 B
    int*   ofs   = cnt + N_NODES;                          //    200,000 B
    int*   bsum  = ofs + N_NODES;                          //      1,024 B (49 used)
    unsigned short* Wt = (unsigned short*)(bsum + 256);    //    221,184 B
    int*   eidx  = (int*)((char*)Wt + 221184);             //  2,000,000 B
    unsigned short* msgs = (unsigned short*)(eidx + N_EDGES); // 128,000,000 B
    const size_t NEED = 25600000ULL + 1024 + 200000 + 200000 + 1024
                      + 221184 + 2000000 + 128000000ULL;
    const int mode = (ws_size >= NEED) ? 1 : 0;

    wt_prepass<<<48, 256, 0, stream>>>(Wf, Ws, Wt);
    if (mode) {
        hipMemsetAsync(stats, 0, 1024 + 200000, stream);   // stats + cnt
        edge_msg_mfma<<<(N_EDGES + BE - 1) / BE, 256, 0, stream>>>(
            x, edge_attr, esrc, etgt, Wt, bf_, bs_, agg, msgs, cnt, 1);
        scan1_kernel<<<49, 1024, 0, stream>>>(cnt, ofs, bsum);
        scan2_kernel<<<1, 64, 0, stream>>>(bsum);
        fill_kernel<<<(N_EDGES + 511) / 512, 512, 0, stream>>>(esrc, ofs, bsum, eidx);
        gather_kernel<<<N_NODES / 2, 256, 0, stream>>>(msgs, eidx, cnt, ofs, bsum, agg);
    } else {
        hipMemsetAsync(d_ws, 0, ((size_t)N_NODES * D + 2 * D) * sizeof(float), stream);
        edge_msg_mfma<<<(N_EDGES + BE - 1) / BE, 256, 0, stream>>>(
            x, edge_attr, esrc, etgt, Wt, bf_, bs_, agg, msgs, cnt, 0);
    }
    bn_stats_kernel<<<STATS_BLOCKS, 256, 0, stream>>>(agg, stats);
    bn_final_kernel<<<(N_NODES * D / 4 + 255) / 256, 256, 0, stream>>>(
        x, agg, stats, gamma, beta, out);
}